// Round 2
// baseline (137.657 us; speedup 1.0000x reference)
//
#include <hip/hip_runtime.h>
#include <hip/hip_fp16.h>

#define BS 2
#define NS 50000
#define CCH 32
#define RR 128
#define SS 8

typedef float v2f __attribute__((ext_vector_type(2)));
typedef _Float16 h2 __attribute__((ext_vector_type(2)));

#if __has_builtin(__builtin_amdgcn_fdot2)
#define HAVE_DOT2 1
#else
#define HAVE_DOT2 0
#endif

// ws layout (NO pair replication -> per-batch planes fit 4 MB per-XCD L2):
//   tp : BS*3*RR*RR blocks of 64 B fp16 transposed planes:
//        block (b,pl,y,x): uint #c2 (c2=0..15) = half(src[2c2][y][x]) | half(src[2c2+1][y][x])<<16
//        total = 6,291,456 B  (3.15 MB per batch < 4 MB L2)
//   Wc : 1024 floats  (W_v @ W_out)   at byte offset 6,291,456
//   bvw: 32 floats    (b_v @ W_out)

__device__ __forceinline__ unsigned pk_rn(float a, float b) {
    unsigned h0 = __half_as_ushort(__float2half(a));
    unsigned h1 = __half_as_ushort(__float2half(b));
    return h0 | (h1 << 16);
}

// blocks 0..767: transpose+convert one (b,pl,y) row via LDS (vectorized in/out).
// blocks 768..771: compute Wc = Wv@Wout and bvw = bv@Wout.
__global__ __launch_bounds__(256)
void prep(const float* __restrict__ cxz,
          const float* __restrict__ cxy,
          const float* __restrict__ cyz,
          const float* __restrict__ Wv, const float* __restrict__ bv,
          const float* __restrict__ Wout,
          unsigned* __restrict__ tp, float* __restrict__ Wc,
          float* __restrict__ bvw) {
    __shared__ float lds[32 * 129];
    int tid = threadIdx.x;
    int row = blockIdx.x;
    if (row < BS * 3 * RR) {
        int y  = row & 127;
        int pl = (row >> 7) % 3;
        int b  = row / 384;
        const float* src = (pl == 0) ? cxz : ((pl == 1) ? cxy : cyz);
        const float* sp = src + (((size_t)(b * CCH)) << 14) + (y << 7);
        // stage: thread covers channel c = tid>>3, 4 float4 chunks
        int c = tid >> 3, xq = tid & 7;
        const float4* s4 = (const float4*)(sp + ((size_t)c << 14));
#pragma unroll
        for (int k = 0; k < 4; ++k) {
            float4 v = s4[xq + 8 * k];
            int x = (xq + 8 * k) << 2;
            lds[c * 129 + x + 0] = v.x;
            lds[c * 129 + x + 1] = v.y;
            lds[c * 129 + x + 2] = v.z;
            lds[c * 129 + x + 3] = v.w;
        }
        __syncthreads();
        // output: 2048 uints per row = 512 uint4; uint #(x<<4)+c2
        uint4* dst = (uint4*)(tp + ((size_t)row << 11));
#pragma unroll
        for (int t = 0; t < 2; ++t) {
            int j = tid + 256 * t;          // uint4 index 0..511
            int x  = j >> 2;
            int cb = (j & 3) << 3;          // starting channel (0,8,16,24)
            uint4 o;
            o.x = pk_rn(lds[(cb + 0) * 129 + x], lds[(cb + 1) * 129 + x]);
            o.y = pk_rn(lds[(cb + 2) * 129 + x], lds[(cb + 3) * 129 + x]);
            o.z = pk_rn(lds[(cb + 4) * 129 + x], lds[(cb + 5) * 129 + x]);
            o.w = pk_rn(lds[(cb + 6) * 129 + x], lds[(cb + 7) * 129 + x]);
            dst[j] = o;
        }
    } else {
        int t = (row - BS * 3 * RR) * 256 + tid;    // 0..1023
        int c = t >> 5, j = t & 31;
        float acc = 0.f;
#pragma unroll
        for (int k = 0; k < 32; ++k) acc += Wv[c * 32 + k] * Wout[k * 32 + j];
        Wc[t] = acc;
        if (t < 32) {
            float a2 = 0.f;
#pragma unroll
            for (int k = 0; k < 32; ++k) a2 += bv[k] * Wout[k * 32 + t];
            bvw[t] = a2;
        }
    }
}

// ---- main kernel: 8 lanes/query (8 queries/wave), lane owns channels 4l..4l+3.
// Plane as uint2*: plane stride 1<<17, y stride 1<<10, x stride 1<<3; lane adds +l.
// One uint2 = lane's 4 channels fp16 at one (plane,y,x) column.

struct f4 { v2f lo, hi; };   // 4 channels

// 6 base offsets (x0 column; x1 = +8 uint2 = offset:64) + 4 fracs
struct Coord {
    int o0, o1, o2, o3, o4, o5;
    float wc0, wc1, wr1, wr2;
};

__device__ __forceinline__ Coord coord(float p0, float p1, float p2) {
    Coord c;
    float x0c = fminf(fmaxf(p0, 0.f), 1.f) * 127.f;
    int i0 = min((int)x0c, 126);
    c.wc0 = x0c - (float)i0;
    float x1c = fminf(fmaxf(p1, 0.f), 1.f) * 127.f;
    int i1 = min((int)x1c, 126);
    c.wc1 = x1c - (float)i1;
    float f1 = floorf(x1c);
    int r10 = (int)f1, r11 = min(r10 + 1, 127);
    c.wr1 = x1c - f1;
    float x2c = fminf(fmaxf(p2, 0.f), 1.f) * 127.f;
    float f2 = floorf(x2c);
    int r20 = (int)f2, r21 = min(r20 + 1, 127);
    c.wr2 = x2c - f2;
    int c0 = i0 << 3, c1 = i1 << 3;
    c.o0 = (r20 << 10) + c0;
    c.o1 = (r21 << 10) + c0;
    c.o2 = (1 << 17) + (r10 << 10) + c0;
    c.o3 = (1 << 17) + (r11 << 10) + c0;
    c.o4 = (2 << 17) + (r20 << 10) + c1;
    c.o5 = (2 << 17) + (r21 << 10) + c1;
    return c;
}

struct Samp12 { uint2 u[12]; };

__device__ __forceinline__ void load6x2(const uint2* __restrict__ P0, Samp12& t,
                                        int o0, int o1, int o2, int o3, int o4, int o5) {
    t.u[0]  = P0[o0]; t.u[1]  = P0[o0 + 8];
    t.u[2]  = P0[o1]; t.u[3]  = P0[o1 + 8];
    t.u[4]  = P0[o2]; t.u[5]  = P0[o2 + 8];
    t.u[6]  = P0[o3]; t.u[7]  = P0[o3 + 8];
    t.u[8]  = P0[o4]; t.u[9]  = P0[o4 + 8];
    t.u[10] = P0[o5]; t.u[11] = P0[o5 + 8];
}

// acc += w * (4 fp16 channels in u)  -> compiler emits v_fma_mix_f32
__device__ __forceinline__ void eval_col(f4& a, uint2 u, float w) {
    __half2 h0 = __builtin_bit_cast(__half2, u.x);
    __half2 h1 = __builtin_bit_cast(__half2, u.y);
    a.lo.x = fmaf(__half2float(h0.x), w, a.lo.x);
    a.lo.y = fmaf(__half2float(h0.y), w, a.lo.y);
    a.hi.x = fmaf(__half2float(h1.x), w, a.hi.x);
    a.hi.y = fmaf(__half2float(h1.y), w, a.hi.y);
}

__device__ __forceinline__ void eval_plane2(f4& a, const uint2* u, float wx, float wy) {
    float wB1 = wx * wy;          // (x1,y1)
    float wB0 = wx - wB1;         // (x1,y0)
    float wA1 = wy - wB1;         // (x0,y1)
    float wA0 = 1.f - wx - wA1;   // (x0,y0)
    eval_col(a, u[0], wA0); eval_col(a, u[1], wB0);
    eval_col(a, u[2], wA1); eval_col(a, u[3], wB1);
}

__device__ __forceinline__ void eval12(const Samp12& t, f4& a,
                                       float wc0, float wc1, float wr1, float wr2) {
    eval_plane2(a, t.u + 0, wc0, wr2);   // XZ
    eval_plane2(a, t.u + 4, wc0, wr1);   // XY
    eval_plane2(a, t.u + 8, wc1, wr2);   // YZ
}

__device__ __forceinline__ unsigned pack2(float a, float b) {
#if HAVE_DOT2
    return __builtin_bit_cast(unsigned, __builtin_amdgcn_cvt_pkrtz(a, b));
#else
    __half2 h = __floats2half2_rn(a, b);
    return __builtin_bit_cast(unsigned, h);
#endif
}

// element idx (0..3 within lane) of f4; compile-time idx.
#define GETE(v, idx) (((idx) & 2) ? (((idx) & 1) ? (v).hi.y : (v).hi.x) \
                                  : (((idx) & 1) ? (v).lo.y : (v).lo.x))
// broadcast channel idx (0..31) across the 8-lane query group (base = tid & 56).
#define GETC(v, idx) __shfl(GETE(v, idx), base | ((idx) >> 2), 64)

__global__ __launch_bounds__(256)
void eda_main(const float* __restrict__ qp, const unsigned* __restrict__ tp,
              const float* __restrict__ Woff, const float* __restrict__ boff,
              const float* __restrict__ Ww, const float* __restrict__ bw,
              const float* __restrict__ Wc, const float* __restrict__ bvw,
              const float* __restrict__ bout, float* __restrict__ out) {
    // sWcat is COLUMN-PERMUTED so lane l's 4 outputs are its own sample's params:
    //   col 4l+e = (e<3) ? W_off col (3l+e) : W_w col l
    // => after cat-matmul, lane l holds (dx,dy,dz,w) of aux sample s=l directly.
    __shared__ float    sWcat[32][32];
    __shared__ unsigned sWc2h[16][32];  // f16-pair packed Wc: [k2][j] = (Wc[2k2][j], Wc[2k2+1][j])
    __shared__ float sbcat[32];         // permuted like sWcat
    __shared__ float sbvw[32];
    __shared__ float sbout[32];

    int tid = threadIdx.x;
    int lane = tid & 7;
    int base = tid & 56;                          // query-group base within wave
    int b  = blockIdx.x & 1;                      // XCD-parity batch split
    int qi = (blockIdx.x >> 1) * 32 + (tid >> 3); // query within batch
    int qq = min(qi, NS - 1);

    const float* p = qp + ((size_t)b * NS + qq) * 3;
    float p0 = p[0], p1 = p[1], p2 = p[2];

    const uint2* P0 = (const uint2*)tp + (((size_t)(b * 3)) << 17) + lane;

    // ---- issue feature tap loads early; they fly during LDS weight staging ----
    Coord fc = coord(p0, p1, p2);
    Samp12 fs;
    load6x2(P0, fs, fc.o0, fc.o1, fc.o2, fc.o3, fc.o4, fc.o5);

    for (int i = tid; i < 1024; i += 256) {
        int k = i >> 5, j = i & 31, l2 = j >> 2, e = j & 3;
        sWcat[k][j] = (e < 3) ? Woff[k * 24 + 3 * l2 + e] : Ww[k * 8 + l2];
    }
    {
        int k2 = tid >> 5, j = tid & 31;          // rows 0..7 and 8..15
        sWc2h[k2][j]     = pack2(Wc[k2 * 64 + j],        Wc[k2 * 64 + 32 + j]);
        sWc2h[k2 + 8][j] = pack2(Wc[(k2 + 8) * 64 + j],  Wc[(k2 + 8) * 64 + 32 + j]);
    }
    if (tid < 32) {
        int l2 = tid >> 2, e = tid & 3;
        sbcat[tid] = (e < 3) ? boff[3 * l2 + e] : bw[l2];
        sbvw[tid]  = bvw[tid];
        sbout[tid] = bout[tid];
    }
    __syncthreads();

    // ---- feature ----
    f4 feat; feat.lo = (v2f){0.f, 0.f}; feat.hi = (v2f){0.f, 0.f};
    eval12(fs, feat, fc.wc0, fc.wc1, fc.wr1, fc.wr2);

    // ---- cat = feature @ [W_off | W_w] (permuted cols) + bias ----
    f4 cat;
    cat.lo.x = sbcat[(lane << 2) + 0]; cat.lo.y = sbcat[(lane << 2) + 1];
    cat.hi.x = sbcat[(lane << 2) + 2]; cat.hi.y = sbcat[(lane << 2) + 3];
#pragma unroll
    for (int k = 0; k < 32; ++k) {
        float fcv = GETC(feat, k);
        const v2f* wp = (const v2f*)&sWcat[k][lane << 2];
        v2f fc2 = {fcv, fcv};
        cat.lo = __builtin_elementwise_fma(fc2, wp[0], cat.lo);
        cat.hi = __builtin_elementwise_fma(fc2, wp[1], cat.hi);
    }

    // ---- per-lane precompute for MY sample (s = lane) ----
    Coord my = coord(p0 + cat.lo.x, p1 + cat.lo.y, p2 + cat.hi.x);
    float wt_my = cat.hi.y;
    unsigned pf01 = pack2(my.wc0, my.wc1);   // fp16 fracs (same precision as before)
    unsigned pf23 = pack2(my.wr1, my.wr2);

    // ---- software-pipelined s-loop: shuffle-distribute sample s's offsets,
    //      prefetch s+1's 12 loads during s's eval ----
    f4 wa; wa.lo = (v2f){0.f, 0.f}; wa.hi = (v2f){0.f, 0.f};
    float wsum = 0.f;
    Samp12 cur, nxt;
    {
        int src = base;   // s = 0
        load6x2(P0, cur, __shfl(my.o0, src, 64), __shfl(my.o1, src, 64),
                         __shfl(my.o2, src, 64), __shfl(my.o3, src, 64),
                         __shfl(my.o4, src, 64), __shfl(my.o5, src, 64));
    }
#pragma unroll
    for (int s = 0; s < SS; ++s) {
        if (s < SS - 1) {
            int src = base | (s + 1);
            load6x2(P0, nxt, __shfl(my.o0, src, 64), __shfl(my.o1, src, 64),
                             __shfl(my.o2, src, 64), __shfl(my.o3, src, 64),
                             __shfl(my.o4, src, 64), __shfl(my.o5, src, 64));
        }
        int src = base | s;
        __half2 f01 = __builtin_bit_cast(__half2, (unsigned)__shfl((int)pf01, src, 64));
        __half2 f23 = __builtin_bit_cast(__half2, (unsigned)__shfl((int)pf23, src, 64));
        float wc0 = __half2float(f01.x), wc1 = __half2float(f01.y);
        float wr1 = __half2float(f23.x), wr2 = __half2float(f23.y);
        f4 aux; aux.lo = (v2f){0.f, 0.f}; aux.hi = (v2f){0.f, 0.f};
        eval12(cur, aux, wc0, wc1, wr1, wr2);
        float wt = __shfl(wt_my, src, 64);
        v2f w2 = {wt, wt};
        wa.lo = __builtin_elementwise_fma(w2, aux.lo, wa.lo);
        wa.hi = __builtin_elementwise_fma(w2, aux.hi, wa.hi);
        wsum += wt;
        if (s < SS - 1) cur = nxt;
    }

    // ---- out = wa @ (W_v@W_out) + wsum*(b_v@W_out) + b_out + feature ----
    f4 o;
    v2f ws2 = {wsum, wsum};
    {
        v2f bo  = {sbout[(lane << 2) + 0], sbout[(lane << 2) + 1]};
        v2f bv2 = {sbvw[(lane << 2) + 0], sbvw[(lane << 2) + 1]};
        o.lo = __builtin_elementwise_fma(ws2, bv2, bo) + feat.lo;
        v2f bo2 = {sbout[(lane << 2) + 2], sbout[(lane << 2) + 3]};
        v2f bv3 = {sbvw[(lane << 2) + 2], sbvw[(lane << 2) + 3]};
        o.hi = __builtin_elementwise_fma(ws2, bv3, bo2) + feat.hi;
    }
    // wa packed as f16 pairs: safe (final non-amplified linear, err ~0.005)
    unsigned pkLo = pack2(wa.lo.x, wa.lo.y);   // channels 4l, 4l+1
    unsigned pkHi = pack2(wa.hi.x, wa.hi.y);   // channels 4l+2, 4l+3
#pragma unroll
    for (int k2 = 0; k2 < 16; ++k2) {
        unsigned wb = (unsigned)__shfl((int)((k2 & 1) ? pkHi : pkLo), base | (k2 >> 1), 64);
        const uint4 wv = *(const uint4*)&sWc2h[k2][lane << 2];
#if HAVE_DOT2
        h2 wp = __builtin_bit_cast(h2, wb);
        o.lo.x = __builtin_amdgcn_fdot2(__builtin_bit_cast(h2, wv.x), wp, o.lo.x, false);
        o.lo.y = __builtin_amdgcn_fdot2(__builtin_bit_cast(h2, wv.y), wp, o.lo.y, false);
        o.hi.x = __builtin_amdgcn_fdot2(__builtin_bit_cast(h2, wv.z), wp, o.hi.x, false);
        o.hi.y = __builtin_amdgcn_fdot2(__builtin_bit_cast(h2, wv.w), wp, o.hi.y, false);
#else
        __half2 hw = __builtin_bit_cast(__half2, wb);
        float a0 = __half2float(hw.x), a1 = __half2float(hw.y);
        __half2 w0 = __builtin_bit_cast(__half2, wv.x);
        __half2 w1 = __builtin_bit_cast(__half2, wv.y);
        __half2 w2_ = __builtin_bit_cast(__half2, wv.z);
        __half2 w3 = __builtin_bit_cast(__half2, wv.w);
        o.lo.x = fmaf(__half2float(w0.y), a1, fmaf(__half2float(w0.x), a0, o.lo.x));
        o.lo.y = fmaf(__half2float(w1.y), a1, fmaf(__half2float(w1.x), a0, o.lo.y));
        o.hi.x = fmaf(__half2float(w2_.y), a1, fmaf(__half2float(w2_.x), a0, o.hi.x));
        o.hi.y = fmaf(__half2float(w3.y), a1, fmaf(__half2float(w3.x), a0, o.hi.y));
#endif
    }

    if (qi < NS) {
        float* dst = out + ((size_t)b * NS + qi) * 32 + (lane << 2);
        *(float4*)dst = make_float4(o.lo.x, o.lo.y, o.hi.x, o.hi.y);
    }
}

extern "C" void kernel_launch(void* const* d_in, const int* in_sizes, int n_in,
                              void* d_out, int out_size, void* d_ws, size_t ws_size,
                              hipStream_t stream) {
    const float* qp   = (const float*)d_in[0];
    const float* cxz  = (const float*)d_in[1];
    const float* cxy  = (const float*)d_in[2];
    const float* cyz  = (const float*)d_in[3];
    const float* Woff = (const float*)d_in[4];
    const float* boff = (const float*)d_in[5];
    const float* Ww   = (const float*)d_in[6];
    const float* bw   = (const float*)d_in[7];
    const float* Wv   = (const float*)d_in[8];
    const float* bv   = (const float*)d_in[9];
    const float* Wout = (const float*)d_in[10];
    const float* bout = (const float*)d_in[11];
    float* out = (float*)d_out;

    unsigned* tp = (unsigned*)d_ws;
    float* Wc  = (float*)((char*)d_ws + (size_t)BS * 3 * RR * RR * CCH * 2);
    float* bvw = Wc + 1024;

    prep<<<BS * 3 * RR + 4, 256, 0, stream>>>(cxz, cxy, cyz, Wv, bv, Wout, tp, Wc, bvw);
    // even blockIdx -> batch 0, odd -> batch 1 (round-robin block->XCD dispatch
    // biases each XCD toward one batch's 3.15 MB planes -> fits 4 MB L2).
    int blocks_per_batch = (NS + 31) / 32;   // 32 queries per 256-thread block
    eda_main<<<2 * blocks_per_batch, 256, 0, stream>>>(qp, tp, Woff, boff, Ww, bw,
                                                       Wc, bvw, bout, out);
}

// Round 3
// 132.185 us; speedup vs baseline: 1.0414x; 1.0414x over previous
//
#include <hip/hip_runtime.h>
#include <hip/hip_fp16.h>

#define BS 2
#define NS 50000
#define CCH 32
#define RR 128
#define SS 8

typedef float v2f __attribute__((ext_vector_type(2)));
typedef _Float16 h2 __attribute__((ext_vector_type(2)));

#if __has_builtin(__builtin_amdgcn_fdot2)
#define HAVE_DOT2 1
#else
#define HAVE_DOT2 0
#endif

// ws layout (pair-replicated fp16 planes; best-measured tap format):
//   tp : BS*3*RR*RR blocks of 128 B:
//        block (b,pl,y,x) holds channels c=0..31 interleaved {col x, col x+1}:
//        uint32 #c = half(src[c][y][x]) | half(src[c][y][min(x+1,127)])<<16
//        = 12,582,912 B
//   Wc : 1024 floats  (W_v @ W_out)
//   bvw: 32 floats    (b_v @ W_out)

__device__ __forceinline__ unsigned pk_rn(float a, float b) {
    unsigned h0 = __half_as_ushort(__float2half(a));
    unsigned h1 = __half_as_ushort(__float2half(b));
    return h0 | (h1 << 16);
}

// blocks 0..767: transpose+convert+replicate one (b,pl,y) row via LDS.
// blocks 768..771: compute Wc = Wv@Wout and bvw = bv@Wout.
__global__ __launch_bounds__(256)
void prep(const float* __restrict__ cxz,
          const float* __restrict__ cxy,
          const float* __restrict__ cyz,
          const float* __restrict__ Wv, const float* __restrict__ bv,
          const float* __restrict__ Wout,
          unsigned* __restrict__ tp, float* __restrict__ Wc,
          float* __restrict__ bvw) {
    __shared__ float lds[32 * 129];
    int tid = threadIdx.x;
    int row = blockIdx.x;
    if (row < BS * 3 * RR) {
        int y  = row & 127;
        int pl = (row >> 7) % 3;
        int b  = row / 384;
        const float* src = (pl == 0) ? cxz : ((pl == 1) ? cxy : cyz);
        const float* sp = src + (((size_t)(b * CCH)) << 14) + (y << 7);
        // stage: thread covers channel c = tid>>3, 4 float4 chunks
        int c = tid >> 3, xq = tid & 7;
        const float4* s4 = (const float4*)(sp + ((size_t)c << 14));
#pragma unroll
        for (int k = 0; k < 4; ++k) {
            float4 v = s4[xq + 8 * k];
            int x = (xq + 8 * k) << 2;
            lds[c * 129 + x + 0] = v.x;
            lds[c * 129 + x + 1] = v.y;
            lds[c * 129 + x + 2] = v.z;
            lds[c * 129 + x + 3] = v.w;
        }
        __syncthreads();
        // output: 4096 uints per row = 1024 uint4; uint #(x<<5)+c
        uint4* dst = (uint4*)(tp + ((size_t)row << 12));
#pragma unroll
        for (int i = 0; i < 4; ++i) {
            int j = tid + 256 * i;          // uint4 index 0..1023
            int x  = j >> 3;
            int c0 = (j & 7) << 2;          // channels c0..c0+3 at column x
            int x1 = min(x + 1, 127);
            uint4 o;
            o.x = pk_rn(lds[(c0 + 0) * 129 + x], lds[(c0 + 0) * 129 + x1]);
            o.y = pk_rn(lds[(c0 + 1) * 129 + x], lds[(c0 + 1) * 129 + x1]);
            o.z = pk_rn(lds[(c0 + 2) * 129 + x], lds[(c0 + 2) * 129 + x1]);
            o.w = pk_rn(lds[(c0 + 3) * 129 + x], lds[(c0 + 3) * 129 + x1]);
            dst[j] = o;
        }
    } else {
        int t = (row - BS * 3 * RR) * 256 + tid;    // 0..1023
        int c = t >> 5, j = t & 31;
        float acc = 0.f;
#pragma unroll
        for (int k = 0; k < 32; ++k) acc += Wv[c * 32 + k] * Wout[k * 32 + j];
        Wc[t] = acc;
        if (t < 32) {
            float a2 = 0.f;
#pragma unroll
            for (int k = 0; k < 32; ++k) a2 += bv[k] * Wout[k * 32 + t];
            bvw[t] = a2;
        }
    }
}

// ---- main kernel: 8 lanes/query (8 queries/wave), lane owns channels 4l..4l+3.
// Plane as uint4*: plane stride 1<<17, y stride 1<<10, x stride 1<<3; lane adds +l.
// One uint4 = lane's 4 channels x {x0, x1} (fp16 interleaved).

struct f4 { v2f lo, hi; };   // 4 channels

// feature tap: 6 row-loads + 4 interpolation fracs (all lanes redundant, once)
struct Samp { uint4 u[6]; float wc0, wc1, wr1, wr2; };
struct SampB { uint4 u[6]; };   // in-flight tap data only (24 VGPR)

__device__ __forceinline__ Samp load_samp(const uint4* __restrict__ P0,
                                          float p0, float p1, float p2) {
    Samp t;
    float x0c = fminf(fmaxf(p0, 0.f), 1.f) * 127.f;
    float x1c = fminf(fmaxf(p1, 0.f), 1.f) * 127.f;
    float x2c = fminf(fmaxf(p2, 0.f), 1.f) * 127.f;
    int i0 = min((int)x0c, 126);
    t.wc0 = x0c - (float)i0;
    int i1 = min((int)x1c, 126);
    t.wc1 = x1c - (float)i1;
    float f1 = floorf(x1c);
    int r10 = (int)f1, r11 = min(r10 + 1, 127);
    t.wr1 = x1c - f1;
    float f2 = floorf(x2c);
    int r20 = (int)f2, r21 = min(r20 + 1, 127);
    t.wr2 = x2c - f2;

    const uint4* Pxz = P0;
    const uint4* Pxy = P0 + (1 << 17);
    const uint4* Pyz = P0 + (2 << 17);
    int c0 = i0 << 3, c1 = i1 << 3;
    int R10 = r10 << 10, R11 = r11 << 10;
    int R20 = r20 << 10, R21 = r21 << 10;
    t.u[0] = Pxz[R20 + c0];  t.u[1] = Pxz[R21 + c0];
    t.u[2] = Pxy[R10 + c0];  t.u[3] = Pxy[R11 + c0];
    t.u[4] = Pyz[R20 + c1];  t.u[5] = Pyz[R21 + c1];
    return t;
}

__device__ __forceinline__ unsigned pack2(float a, float b) {
#if HAVE_DOT2
    return __builtin_bit_cast(unsigned, __builtin_amdgcn_cvt_pkrtz(a, b));
#else
    __half2 h = __floats2half2_rn(a, b);
    return __builtin_bit_cast(unsigned, h);
#endif
}

#if HAVE_DOT2
__device__ __forceinline__ void eval_row(f4& acc, uint4 u, h2 w) {
    acc.lo.x = __builtin_amdgcn_fdot2(__builtin_bit_cast(h2, u.x), w, acc.lo.x, false);
    acc.lo.y = __builtin_amdgcn_fdot2(__builtin_bit_cast(h2, u.y), w, acc.lo.y, false);
    acc.hi.x = __builtin_amdgcn_fdot2(__builtin_bit_cast(h2, u.z), w, acc.hi.x, false);
    acc.hi.y = __builtin_amdgcn_fdot2(__builtin_bit_cast(h2, u.w), w, acc.hi.y, false);
}

__device__ __forceinline__ void eval_plane(f4& acc, uint4 ua, uint4 ub,
                                           float wx, float wy) {
    float wB1 = wx * wy;          // (x1,y1)
    float wB0 = wx - wB1;         // (x1,y0)
    float wA1 = wy - wB1;         // (x0,y1)
    float wA0 = 1.f - wx - wA1;   // (x0,y0)
    h2 w0 = __builtin_bit_cast(h2, __builtin_amdgcn_cvt_pkrtz(wA0, wB0));
    h2 w1 = __builtin_bit_cast(h2, __builtin_amdgcn_cvt_pkrtz(wA1, wB1));
    eval_row(acc, ua, w0);
    eval_row(acc, ub, w1);
}

__device__ __forceinline__ void eval_rowp(f4& acc, uint4 u, unsigned pw) {
    eval_row(acc, u, __builtin_bit_cast(h2, pw));
}
#else
__device__ __forceinline__ void eval_row(f4& acc, uint4 u, float wA, float wB) {
    __half2 h0 = __builtin_bit_cast(__half2, u.x);
    __half2 h1 = __builtin_bit_cast(__half2, u.y);
    __half2 h2_ = __builtin_bit_cast(__half2, u.z);
    __half2 h3 = __builtin_bit_cast(__half2, u.w);
    acc.lo.x = fmaf(__half2float(h0.y), wB, fmaf(__half2float(h0.x), wA, acc.lo.x));
    acc.lo.y = fmaf(__half2float(h1.y), wB, fmaf(__half2float(h1.x), wA, acc.lo.y));
    acc.hi.x = fmaf(__half2float(h2_.y), wB, fmaf(__half2float(h2_.x), wA, acc.hi.x));
    acc.hi.y = fmaf(__half2float(h3.y), wB, fmaf(__half2float(h3.x), wA, acc.hi.y));
}

__device__ __forceinline__ void eval_plane(f4& acc, uint4 ua, uint4 ub,
                                           float wx, float wy) {
    float wB1 = wx * wy;
    float wB0 = wx - wB1;
    float wA1 = wy - wB1;
    float wA0 = 1.f - wx - wA1;
    eval_row(acc, ua, wA0, wB0);
    eval_row(acc, ub, wA1, wB1);
}

__device__ __forceinline__ void eval_rowp(f4& acc, uint4 u, unsigned pw) {
    __half2 hw = __builtin_bit_cast(__half2, pw);
    eval_row(acc, u, __half2float(hw.x), __half2float(hw.y));
}
#endif

__device__ __forceinline__ void eval_samp(const Samp& t, f4& acc) {
    eval_plane(acc, t.u[0], t.u[1], t.wc0, t.wr2);   // XZ
    eval_plane(acc, t.u[2], t.u[3], t.wc0, t.wr1);   // XY
    eval_plane(acc, t.u[4], t.u[5], t.wc1, t.wr2);   // YZ
}

// element idx (0..3 within lane) of f4; compile-time idx.
#define GETE(v, idx) (((idx) & 2) ? (((idx) & 1) ? (v).hi.y : (v).hi.x) \
                                  : (((idx) & 1) ? (v).lo.y : (v).lo.x))
// broadcast channel idx (0..31) across the 8-lane query group (base = tid & 56).
#define GETC(v, idx) __shfl(GETE(v, idx), base | ((idx) >> 2), 64)

__global__ __launch_bounds__(256)
void eda_main(const float* __restrict__ qp, const unsigned* __restrict__ tp,
              const float* __restrict__ Woff, const float* __restrict__ boff,
              const float* __restrict__ Ww, const float* __restrict__ bw,
              const float* __restrict__ Wc, const float* __restrict__ bvw,
              const float* __restrict__ bout, float* __restrict__ out) {
    // sWcat is COLUMN-PERMUTED so lane l's 4 outputs are its own sample's params:
    //   col 4l+e = (e<3) ? W_off col (3l+e) : W_w col l
    // => after cat-matmul, lane l holds (dx,dy,dz,w) of aux sample s=l directly.
    __shared__ float    sWcat[32][32];
    __shared__ unsigned sWc2h[16][32];  // f16-pair packed Wc: [k2][j] = (Wc[2k2][j], Wc[2k2+1][j])
    __shared__ float sbcat[32];         // permuted like sWcat
    __shared__ float sbvw[32];
    __shared__ float sbout[32];

    int tid = threadIdx.x;
    int lane = tid & 7;
    int base = tid & 56;                          // query-group base within wave
    int b  = blockIdx.x & 1;                      // XCD-parity batch split
    int qi = (blockIdx.x >> 1) * 32 + (tid >> 3); // query within batch
    int qq = min(qi, NS - 1);

    const float* p = qp + ((size_t)b * NS + qq) * 3;
    float p0 = p[0], p1 = p[1], p2 = p[2];

    const uint4* P0 = (const uint4*)tp + (((size_t)(b * 3)) << 17) + lane;

    // ---- issue feature tap loads early; they fly during LDS weight staging ----
    Samp fs = load_samp(P0, p0, p1, p2);

    for (int i = tid; i < 1024; i += 256) {
        int k = i >> 5, j = i & 31, l2 = j >> 2, e = j & 3;
        sWcat[k][j] = (e < 3) ? Woff[k * 24 + 3 * l2 + e] : Ww[k * 8 + l2];
    }
    {
        int k2 = tid >> 5, j = tid & 31;          // rows 0..7 and 8..15
        sWc2h[k2][j]     = pack2(Wc[k2 * 64 + j],        Wc[k2 * 64 + 32 + j]);
        sWc2h[k2 + 8][j] = pack2(Wc[(k2 + 8) * 64 + j],  Wc[(k2 + 8) * 64 + 32 + j]);
    }
    if (tid < 32) {
        int l2 = tid >> 2, e = tid & 3;
        sbcat[tid] = (e < 3) ? boff[3 * l2 + e] : bw[l2];
        sbvw[tid]  = bvw[tid];
        sbout[tid] = bout[tid];
    }
    __syncthreads();

    // ---- feature ----
    f4 feat; feat.lo = (v2f){0.f, 0.f}; feat.hi = (v2f){0.f, 0.f};
    eval_samp(fs, feat);

    // ---- cat = feature @ [W_off | W_w] (permuted cols) + bias ----
    f4 cat;
    cat.lo.x = sbcat[(lane << 2) + 0]; cat.lo.y = sbcat[(lane << 2) + 1];
    cat.hi.x = sbcat[(lane << 2) + 2]; cat.hi.y = sbcat[(lane << 2) + 3];
#pragma unroll
    for (int k = 0; k < 32; ++k) {
        float fcv = GETC(feat, k);
        const v2f* wp = (const v2f*)&sWcat[k][lane << 2];
        v2f fc2 = {fcv, fcv};
        cat.lo = __builtin_elementwise_fma(fc2, wp[0], cat.lo);
        cat.hi = __builtin_elementwise_fma(fc2, wp[1], cat.hi);
    }

    // ---- per-lane precompute for MY sample (s = lane): offsets + wt-premultiplied
    //      packed corner weights (so the s-loop needs no aux acc / wt fma) ----
    float sx = p0 + cat.lo.x, sy = p1 + cat.lo.y, sz = p2 + cat.hi.x;
    float wt_my = cat.hi.y;
    float x0c = fminf(fmaxf(sx, 0.f), 1.f) * 127.f;
    int  i0 = min((int)x0c, 126);
    float wc0 = x0c - (float)i0;
    float x1c = fminf(fmaxf(sy, 0.f), 1.f) * 127.f;
    int  i1 = min((int)x1c, 126);
    float wc1 = x1c - (float)i1;
    float f1 = floorf(x1c);
    int r10 = (int)f1, r11 = min(r10 + 1, 127);
    float wr1 = x1c - f1;
    float x2c = fminf(fmaxf(sz, 0.f), 1.f) * 127.f;
    float f2 = floorf(x2c);
    int r20 = (int)f2, r21 = min(r20 + 1, 127);
    float wr2 = x2c - f2;
    int c0 = i0 << 3, c1 = i1 << 3;
    int o0 = (r20 << 10) + c0;
    int o1 = (r21 << 10) + c0;
    int o2 = (1 << 17) + (r10 << 10) + c0;
    int o3 = (1 << 17) + (r11 << 10) + c0;
    int o4 = (2 << 17) + (r20 << 10) + c1;
    int o5 = (2 << 17) + (r21 << 10) + c1;
    unsigned m0, m1, m2, m3, m4, m5;
    { float wB1 = wc0 * wr2, wB0 = wc0 - wB1, wA1 = wr2 - wB1, wA0 = 1.f - wc0 - wA1;
      m0 = pack2(wA0 * wt_my, wB0 * wt_my); m1 = pack2(wA1 * wt_my, wB1 * wt_my); }  // XZ
    { float wB1 = wc0 * wr1, wB0 = wc0 - wB1, wA1 = wr1 - wB1, wA0 = 1.f - wc0 - wA1;
      m2 = pack2(wA0 * wt_my, wB0 * wt_my); m3 = pack2(wA1 * wt_my, wB1 * wt_my); }  // XY
    { float wB1 = wc1 * wr2, wB0 = wc1 - wB1, wA1 = wr2 - wB1, wA0 = 1.f - wc1 - wA1;
      m4 = pack2(wA0 * wt_my, wB0 * wt_my); m5 = pack2(wA1 * wt_my, wB1 * wt_my); }  // YZ

    // wsum = sum of group's 8 sample weights (butterfly within 8-lane group)
    float wsum = wt_my;
    wsum += __shfl_xor(wsum, 1, 64);
    wsum += __shfl_xor(wsum, 2, 64);
    wsum += __shfl_xor(wsum, 4, 64);

    // ---- s-loop, depth-2 software pipeline; fdot2 accumulates straight into wa ----
    f4 wa; wa.lo = (v2f){0.f, 0.f}; wa.hi = (v2f){0.f, 0.f};
    SampB sA, sB;
    {
        int src = base;        // s = 0
        sA.u[0] = P0[__shfl(o0, src, 64)]; sA.u[1] = P0[__shfl(o1, src, 64)];
        sA.u[2] = P0[__shfl(o2, src, 64)]; sA.u[3] = P0[__shfl(o3, src, 64)];
        sA.u[4] = P0[__shfl(o4, src, 64)]; sA.u[5] = P0[__shfl(o5, src, 64)];
    }
    {
        int src = base | 1;    // s = 1
        sB.u[0] = P0[__shfl(o0, src, 64)]; sB.u[1] = P0[__shfl(o1, src, 64)];
        sB.u[2] = P0[__shfl(o2, src, 64)]; sB.u[3] = P0[__shfl(o3, src, 64)];
        sB.u[4] = P0[__shfl(o4, src, 64)]; sB.u[5] = P0[__shfl(o5, src, 64)];
    }
#pragma unroll
    for (int s = 0; s < SS; ++s) {
        SampB sC;
        if (s + 2 < SS) {
            int src = base | (s + 2);
            sC.u[0] = P0[__shfl(o0, src, 64)]; sC.u[1] = P0[__shfl(o1, src, 64)];
            sC.u[2] = P0[__shfl(o2, src, 64)]; sC.u[3] = P0[__shfl(o3, src, 64)];
            sC.u[4] = P0[__shfl(o4, src, 64)]; sC.u[5] = P0[__shfl(o5, src, 64)];
        }
        int src = base | s;
        eval_rowp(wa, sA.u[0], (unsigned)__shfl((int)m0, src, 64));
        eval_rowp(wa, sA.u[1], (unsigned)__shfl((int)m1, src, 64));
        eval_rowp(wa, sA.u[2], (unsigned)__shfl((int)m2, src, 64));
        eval_rowp(wa, sA.u[3], (unsigned)__shfl((int)m3, src, 64));
        eval_rowp(wa, sA.u[4], (unsigned)__shfl((int)m4, src, 64));
        eval_rowp(wa, sA.u[5], (unsigned)__shfl((int)m5, src, 64));
        if (s + 1 < SS) {
            sA = sB;
            if (s + 2 < SS) sB = sC;
        }
    }

    // ---- out = wa @ (W_v@W_out) + wsum*(b_v@W_out) + b_out + feature ----
    f4 o;
    v2f ws2 = {wsum, wsum};
    {
        v2f bo  = {sbout[(lane << 2) + 0], sbout[(lane << 2) + 1]};
        v2f bv2 = {sbvw[(lane << 2) + 0], sbvw[(lane << 2) + 1]};
        o.lo = __builtin_elementwise_fma(ws2, bv2, bo) + feat.lo;
        v2f bo2 = {sbout[(lane << 2) + 2], sbout[(lane << 2) + 3]};
        v2f bv3 = {sbvw[(lane << 2) + 2], sbvw[(lane << 2) + 3]};
        o.hi = __builtin_elementwise_fma(ws2, bv3, bo2) + feat.hi;
    }
    // wa packed as f16 pairs: safe (final non-amplified linear, err ~0.005)
    unsigned pkLo = pack2(wa.lo.x, wa.lo.y);   // channels 4l, 4l+1
    unsigned pkHi = pack2(wa.hi.x, wa.hi.y);   // channels 4l+2, 4l+3
#pragma unroll
    for (int k2 = 0; k2 < 16; ++k2) {
        unsigned wb = (unsigned)__shfl((int)((k2 & 1) ? pkHi : pkLo), base | (k2 >> 1), 64);
        const uint4 wv = *(const uint4*)&sWc2h[k2][lane << 2];
#if HAVE_DOT2
        h2 wp = __builtin_bit_cast(h2, wb);
        o.lo.x = __builtin_amdgcn_fdot2(__builtin_bit_cast(h2, wv.x), wp, o.lo.x, false);
        o.lo.y = __builtin_amdgcn_fdot2(__builtin_bit_cast(h2, wv.y), wp, o.lo.y, false);
        o.hi.x = __builtin_amdgcn_fdot2(__builtin_bit_cast(h2, wv.z), wp, o.hi.x, false);
        o.hi.y = __builtin_amdgcn_fdot2(__builtin_bit_cast(h2, wv.w), wp, o.hi.y, false);
#else
        __half2 hw = __builtin_bit_cast(__half2, wb);
        float a0 = __half2float(hw.x), a1 = __half2float(hw.y);
        __half2 w0 = __builtin_bit_cast(__half2, wv.x);
        __half2 w1 = __builtin_bit_cast(__half2, wv.y);
        __half2 w2_ = __builtin_bit_cast(__half2, wv.z);
        __half2 w3 = __builtin_bit_cast(__half2, wv.w);
        o.lo.x = fmaf(__half2float(w0.y), a1, fmaf(__half2float(w0.x), a0, o.lo.x));
        o.lo.y = fmaf(__half2float(w1.y), a1, fmaf(__half2float(w1.x), a0, o.lo.y));
        o.hi.x = fmaf(__half2float(w2_.y), a1, fmaf(__half2float(w2_.x), a0, o.hi.x));
        o.hi.y = fmaf(__half2float(w3.y), a1, fmaf(__half2float(w3.x), a0, o.hi.y));
#endif
    }

    if (qi < NS) {
        float* dst = out + ((size_t)b * NS + qi) * 32 + (lane << 2);
        *(float4*)dst = make_float4(o.lo.x, o.lo.y, o.hi.x, o.hi.y);
    }
}

extern "C" void kernel_launch(void* const* d_in, const int* in_sizes, int n_in,
                              void* d_out, int out_size, void* d_ws, size_t ws_size,
                              hipStream_t stream) {
    const float* qp   = (const float*)d_in[0];
    const float* cxz  = (const float*)d_in[1];
    const float* cxy  = (const float*)d_in[2];
    const float* cyz  = (const float*)d_in[3];
    const float* Woff = (const float*)d_in[4];
    const float* boff = (const float*)d_in[5];
    const float* Ww   = (const float*)d_in[6];
    const float* bw   = (const float*)d_in[7];
    const float* Wv   = (const float*)d_in[8];
    const float* bv   = (const float*)d_in[9];
    const float* Wout = (const float*)d_in[10];
    const float* bout = (const float*)d_in[11];
    float* out = (float*)d_out;

    unsigned* tp = (unsigned*)d_ws;
    float* Wc  = (float*)((char*)d_ws + (size_t)BS * 3 * RR * RR * CCH * 4);
    float* bvw = Wc + 1024;

    prep<<<BS * 3 * RR + 4, 256, 0, stream>>>(cxz, cxy, cyz, Wv, bv, Wout, tp, Wc, bvw);
    // even blockIdx -> batch 0, odd -> batch 1 (round-robin block->XCD dispatch
    // biases each XCD toward one batch's planes).
    int blocks_per_batch = (NS + 31) / 32;   // 32 queries per 256-thread block
    eda_main<<<2 * blocks_per_batch, 256, 0, stream>>>(qp, tp, Woff, boff, Ww, bw,
                                                       Wc, bvw, bout, out);
}

// Round 5
// 130.117 us; speedup vs baseline: 1.0579x; 1.0159x over previous
//
#include <hip/hip_runtime.h>
#include <hip/hip_fp16.h>

#define BS 2
#define NS 50000
#define CCH 32
#define RR 128
#define SS 8

typedef float v2f __attribute__((ext_vector_type(2)));
typedef _Float16 h2 __attribute__((ext_vector_type(2)));

#if __has_builtin(__builtin_amdgcn_fdot2)
#define HAVE_DOT2 1
#else
#define HAVE_DOT2 0
#endif

// ws layout (pair-replicated fp16 planes; best-measured tap format):
//   tp : BS*3*RR*RR blocks of 128 B:
//        block (b,pl,y,x) holds channels c=0..31 interleaved {col x, col x+1}:
//        uint32 #c = half(src[c][y][x]) | half(src[c][y][min(x+1,127)])<<16
//        = 12,582,912 B
//   Wc : 1024 floats  (W_v @ W_out)
//   bvw: 32 floats    (b_v @ W_out)

__device__ __forceinline__ unsigned pk_rn(float a, float b) {
    unsigned h0 = __half_as_ushort(__float2half(a));
    unsigned h1 = __half_as_ushort(__float2half(b));
    return h0 | (h1 << 16);
}

// blocks 0..767: transpose+convert+replicate one (b,pl,y) row via LDS.
// blocks 768..771: compute Wc = Wv@Wout and bvw = bv@Wout.
__global__ __launch_bounds__(256)
void prep(const float* __restrict__ cxz,
          const float* __restrict__ cxy,
          const float* __restrict__ cyz,
          const float* __restrict__ Wv, const float* __restrict__ bv,
          const float* __restrict__ Wout,
          unsigned* __restrict__ tp, float* __restrict__ Wc,
          float* __restrict__ bvw) {
    __shared__ float lds[32 * 129];
    int tid = threadIdx.x;
    int row = blockIdx.x;
    if (row < BS * 3 * RR) {
        int y  = row & 127;
        int pl = (row >> 7) % 3;
        int b  = row / 384;
        const float* src = (pl == 0) ? cxz : ((pl == 1) ? cxy : cyz);
        const float* sp = src + (((size_t)(b * CCH)) << 14) + (y << 7);
        // stage: thread covers channel c = tid>>3, 4 float4 chunks
        int c = tid >> 3, xq = tid & 7;
        const float4* s4 = (const float4*)(sp + ((size_t)c << 14));
#pragma unroll
        for (int k = 0; k < 4; ++k) {
            float4 v = s4[xq + 8 * k];
            int x = (xq + 8 * k) << 2;
            lds[c * 129 + x + 0] = v.x;
            lds[c * 129 + x + 1] = v.y;
            lds[c * 129 + x + 2] = v.z;
            lds[c * 129 + x + 3] = v.w;
        }
        __syncthreads();
        // output: 4096 uints per row = 1024 uint4; uint #(x<<5)+c
        uint4* dst = (uint4*)(tp + ((size_t)row << 12));
#pragma unroll
        for (int i = 0; i < 4; ++i) {
            int j = tid + 256 * i;          // uint4 index 0..1023
            int x  = j >> 3;
            int c0 = (j & 7) << 2;          // channels c0..c0+3 at column x
            int x1 = min(x + 1, 127);
            uint4 o;
            o.x = pk_rn(lds[(c0 + 0) * 129 + x], lds[(c0 + 0) * 129 + x1]);
            o.y = pk_rn(lds[(c0 + 1) * 129 + x], lds[(c0 + 1) * 129 + x1]);
            o.z = pk_rn(lds[(c0 + 2) * 129 + x], lds[(c0 + 2) * 129 + x1]);
            o.w = pk_rn(lds[(c0 + 3) * 129 + x], lds[(c0 + 3) * 129 + x1]);
            dst[j] = o;
        }
    } else {
        int t = (row - BS * 3 * RR) * 256 + tid;    // 0..1023
        int c = t >> 5, j = t & 31;
        float acc = 0.f;
#pragma unroll
        for (int k = 0; k < 32; ++k) acc += Wv[c * 32 + k] * Wout[k * 32 + j];
        Wc[t] = acc;
        if (t < 32) {
            float a2 = 0.f;
#pragma unroll
            for (int k = 0; k < 32; ++k) a2 += bv[k] * Wout[k * 32 + t];
            bvw[t] = a2;
        }
    }
}

// ---- main kernel: 8 lanes/query (8 queries/wave), lane owns channels 4l..4l+3.
// Plane base tpb is WAVE-UNIFORM (char*); all tap addressing via 32-bit BYTE
// offsets (+ lane*16), so the compiler emits global_load_dwordx4 v,voff,s[base]
// (SGPR base + 32-bit voffset) instead of 64-bit VGPR address math per load.
// Byte offsets: plane stride 1<<21, y stride 1<<14, x stride 1<<7.

struct f4 { v2f lo, hi; };   // 4 channels

// 6 byte-offsets (lane-independent) + 4 interpolation fracs
struct Coord {
    int o0, o1, o2, o3, o4, o5;
    float wc0, wc1, wr1, wr2;
};

__device__ __forceinline__ Coord coord(float p0, float p1, float p2) {
    Coord c;
    float x0c = fminf(fmaxf(p0, 0.f), 1.f) * 127.f;
    int i0 = min((int)x0c, 126);
    c.wc0 = x0c - (float)i0;
    float x1c = fminf(fmaxf(p1, 0.f), 1.f) * 127.f;
    int i1 = min((int)x1c, 126);
    c.wc1 = x1c - (float)i1;
    float f1 = floorf(x1c);
    int r10 = (int)f1, r11 = min(r10 + 1, 127);
    c.wr1 = x1c - f1;
    float x2c = fminf(fmaxf(p2, 0.f), 1.f) * 127.f;
    float f2 = floorf(x2c);
    int r20 = (int)f2, r21 = min(r20 + 1, 127);
    c.wr2 = x2c - f2;
    int c0 = i0 << 7, c1 = i1 << 7;
    c.o0 = (r20 << 14) + c0;
    c.o1 = (r21 << 14) + c0;
    c.o2 = (1 << 21) + (r10 << 14) + c0;
    c.o3 = (1 << 21) + (r11 << 14) + c0;
    c.o4 = (2 << 21) + (r20 << 14) + c1;
    c.o5 = (2 << 21) + (r21 << 14) + c1;
    return c;
}

__device__ __forceinline__ uint4 ldtap(const char* __restrict__ tpb, int off) {
    return *(const uint4*)(tpb + off);
}

struct SampB { uint4 u[6]; };   // in-flight tap data (24 VGPR)

__device__ __forceinline__ unsigned pack2(float a, float b) {
#if HAVE_DOT2
    return __builtin_bit_cast(unsigned, __builtin_amdgcn_cvt_pkrtz(a, b));
#else
    __half2 h = __floats2half2_rn(a, b);
    return __builtin_bit_cast(unsigned, h);
#endif
}

#if HAVE_DOT2
__device__ __forceinline__ void eval_row(f4& acc, uint4 u, h2 w) {
    acc.lo.x = __builtin_amdgcn_fdot2(__builtin_bit_cast(h2, u.x), w, acc.lo.x, false);
    acc.lo.y = __builtin_amdgcn_fdot2(__builtin_bit_cast(h2, u.y), w, acc.lo.y, false);
    acc.hi.x = __builtin_amdgcn_fdot2(__builtin_bit_cast(h2, u.z), w, acc.hi.x, false);
    acc.hi.y = __builtin_amdgcn_fdot2(__builtin_bit_cast(h2, u.w), w, acc.hi.y, false);
}

__device__ __forceinline__ void eval_plane(f4& acc, uint4 ua, uint4 ub,
                                           float wx, float wy) {
    float wB1 = wx * wy;          // (x1,y1)
    float wB0 = wx - wB1;         // (x1,y0)
    float wA1 = wy - wB1;         // (x0,y1)
    float wA0 = 1.f - wx - wA1;   // (x0,y0)
    h2 w0 = __builtin_bit_cast(h2, __builtin_amdgcn_cvt_pkrtz(wA0, wB0));
    h2 w1 = __builtin_bit_cast(h2, __builtin_amdgcn_cvt_pkrtz(wA1, wB1));
    eval_row(acc, ua, w0);
    eval_row(acc, ub, w1);
}

__device__ __forceinline__ void eval_rowp(f4& acc, uint4 u, unsigned pw) {
    eval_row(acc, u, __builtin_bit_cast(h2, pw));
}

__device__ __forceinline__ void dot2_4(f4& acc, uint4 wv, unsigned pw) {
    h2 w = __builtin_bit_cast(h2, pw);
    acc.lo.x = __builtin_amdgcn_fdot2(__builtin_bit_cast(h2, wv.x), w, acc.lo.x, false);
    acc.lo.y = __builtin_amdgcn_fdot2(__builtin_bit_cast(h2, wv.y), w, acc.lo.y, false);
    acc.hi.x = __builtin_amdgcn_fdot2(__builtin_bit_cast(h2, wv.z), w, acc.hi.x, false);
    acc.hi.y = __builtin_amdgcn_fdot2(__builtin_bit_cast(h2, wv.w), w, acc.hi.y, false);
}
#else
__device__ __forceinline__ void eval_row(f4& acc, uint4 u, float wA, float wB) {
    __half2 h0 = __builtin_bit_cast(__half2, u.x);
    __half2 h1 = __builtin_bit_cast(__half2, u.y);
    __half2 h2_ = __builtin_bit_cast(__half2, u.z);
    __half2 h3 = __builtin_bit_cast(__half2, u.w);
    acc.lo.x = fmaf(__half2float(h0.y), wB, fmaf(__half2float(h0.x), wA, acc.lo.x));
    acc.lo.y = fmaf(__half2float(h1.y), wB, fmaf(__half2float(h1.x), wA, acc.lo.y));
    acc.hi.x = fmaf(__half2float(h2_.y), wB, fmaf(__half2float(h2_.x), wA, acc.hi.x));
    acc.hi.y = fmaf(__half2float(h3.y), wB, fmaf(__half2float(h3.x), wA, acc.hi.y));
}

__device__ __forceinline__ void eval_plane(f4& acc, uint4 ua, uint4 ub,
                                           float wx, float wy) {
    float wB1 = wx * wy;
    float wB0 = wx - wB1;
    float wA1 = wy - wB1;
    float wA0 = 1.f - wx - wA1;
    eval_row(acc, ua, wA0, wB0);
    eval_row(acc, ub, wA1, wB1);
}

__device__ __forceinline__ void eval_rowp(f4& acc, uint4 u, unsigned pw) {
    __half2 hw = __builtin_bit_cast(__half2, pw);
    eval_row(acc, u, __half2float(hw.x), __half2float(hw.y));
}

__device__ __forceinline__ void dot2_4(f4& acc, uint4 wv, unsigned pw) {
    __half2 hw = __builtin_bit_cast(__half2, pw);
    float a0 = __half2float(hw.x), a1 = __half2float(hw.y);
    __half2 w0 = __builtin_bit_cast(__half2, wv.x);
    __half2 w1 = __builtin_bit_cast(__half2, wv.y);
    __half2 w2_ = __builtin_bit_cast(__half2, wv.z);
    __half2 w3 = __builtin_bit_cast(__half2, wv.w);
    acc.lo.x = fmaf(__half2float(w0.y), a1, fmaf(__half2float(w0.x), a0, acc.lo.x));
    acc.lo.y = fmaf(__half2float(w1.y), a1, fmaf(__half2float(w1.x), a0, acc.lo.y));
    acc.hi.x = fmaf(__half2float(w2_.y), a1, fmaf(__half2float(w2_.x), a0, acc.hi.x));
    acc.hi.y = fmaf(__half2float(w3.y), a1, fmaf(__half2float(w3.x), a0, acc.hi.y));
}
#endif

// element idx (0..3 within lane) of f4; compile-time idx.
#define GETE(v, idx) (((idx) & 2) ? (((idx) & 1) ? (v).hi.y : (v).hi.x) \
                                  : (((idx) & 1) ? (v).lo.y : (v).lo.x))
// broadcast channel idx (0..31) across the 8-lane query group (base = tid & 56).
#define GETC(v, idx) __shfl(GETE(v, idx), base | ((idx) >> 2), 64)

__global__ __launch_bounds__(256)
void eda_main(const float* __restrict__ qp, const unsigned* __restrict__ tp,
              const float* __restrict__ Woff, const float* __restrict__ boff,
              const float* __restrict__ Ww, const float* __restrict__ bw,
              const float* __restrict__ Wc, const float* __restrict__ bvw,
              const float* __restrict__ bout, float* __restrict__ out) {
    // sWcat is COLUMN-PERMUTED, kept in F32 (offsets are gradient-amplified;
    // fp16 here failed absmax in R4):
    //   col 4l+e = (e<3) ? W_off col (3l+e) : W_w col l
    // => after cat-matmul, lane l holds (dx,dy,dz,w) of aux sample s=l directly.
    __shared__ float    sWcat[32][32];
    __shared__ unsigned sWc2h[16][32];  // f16-pair packed Wc: [k2][j] = (Wc[2k2][j], Wc[2k2+1][j])
    __shared__ float sbcat[32];         // permuted like sWcat cols
    __shared__ float sbvw[32];
    __shared__ float sbout[32];

    int tid = threadIdx.x;
    int lane = tid & 7;
    int lane16 = lane << 4;
    int base = tid & 56;                          // query-group base within wave
    int b  = blockIdx.x & 1;                      // XCD-parity batch split
    int qi = (blockIdx.x >> 1) * 32 + (tid >> 3); // query within batch
    int qq = min(qi, NS - 1);

    const float* p = qp + ((size_t)b * NS + qq) * 3;
    float p0 = p[0], p1 = p[1], p2 = p[2];

    // wave-uniform plane base (batch select); all taps use 32-bit byte offsets
    const char* tpb = (const char*)tp + ((size_t)(b * 3) << 21);

    // ---- issue feature tap loads early; they fly during LDS weight staging ----
    Coord fc = coord(p0, p1, p2);
    SampB fs;
    fs.u[0] = ldtap(tpb, fc.o0 + lane16); fs.u[1] = ldtap(tpb, fc.o1 + lane16);
    fs.u[2] = ldtap(tpb, fc.o2 + lane16); fs.u[3] = ldtap(tpb, fc.o3 + lane16);
    fs.u[4] = ldtap(tpb, fc.o4 + lane16); fs.u[5] = ldtap(tpb, fc.o5 + lane16);

    for (int i = tid; i < 1024; i += 256) {
        int k = i >> 5, j = i & 31, l2 = j >> 2, e = j & 3;
        sWcat[k][j] = (e < 3) ? Woff[k * 24 + 3 * l2 + e] : Ww[k * 8 + l2];
    }
    {
        int k2 = tid >> 5, j = tid & 31;          // rows 0..7 and 8..15
        sWc2h[k2][j]     = pk_rn(Wc[k2 * 64 + j],        Wc[k2 * 64 + 32 + j]);
        sWc2h[k2 + 8][j] = pk_rn(Wc[(k2 + 8) * 64 + j],  Wc[(k2 + 8) * 64 + 32 + j]);
    }
    if (tid < 32) {
        int l2 = tid >> 2, e = tid & 3;
        sbcat[tid] = (e < 3) ? boff[3 * l2 + e] : bw[l2];
        sbvw[tid]  = bvw[tid];
        sbout[tid] = bout[tid];
    }
    __syncthreads();

    // ---- feature ----
    f4 feat; feat.lo = (v2f){0.f, 0.f}; feat.hi = (v2f){0.f, 0.f};
    eval_plane(feat, fs.u[0], fs.u[1], fc.wc0, fc.wr2);   // XZ
    eval_plane(feat, fs.u[2], fs.u[3], fc.wc0, fc.wr1);   // XY
    eval_plane(feat, fs.u[4], fs.u[5], fc.wc1, fc.wr2);   // YZ

    // ---- cat = feature @ [W_off | W_w] (permuted cols, F32) + bias ----
    f4 cat;
    cat.lo.x = sbcat[(lane << 2) + 0]; cat.lo.y = sbcat[(lane << 2) + 1];
    cat.hi.x = sbcat[(lane << 2) + 2]; cat.hi.y = sbcat[(lane << 2) + 3];
#pragma unroll
    for (int k = 0; k < 32; ++k) {
        float fcv = GETC(feat, k);
        const v2f* wp = (const v2f*)&sWcat[k][lane << 2];
        v2f fc2 = {fcv, fcv};
        cat.lo = __builtin_elementwise_fma(fc2, wp[0], cat.lo);
        cat.hi = __builtin_elementwise_fma(fc2, wp[1], cat.hi);
    }

    // ---- per-lane precompute for MY sample (s = lane): byte offsets +
    //      wt-premultiplied packed corner weights ----
    Coord my = coord(p0 + cat.lo.x, p1 + cat.lo.y, p2 + cat.hi.x);
    float wt_my = cat.hi.y;
    unsigned m0, m1, m2, m3, m4, m5;
    { float wB1 = my.wc0 * my.wr2, wB0 = my.wc0 - wB1, wA1 = my.wr2 - wB1, wA0 = 1.f - my.wc0 - wA1;
      m0 = pack2(wA0 * wt_my, wB0 * wt_my); m1 = pack2(wA1 * wt_my, wB1 * wt_my); }  // XZ
    { float wB1 = my.wc0 * my.wr1, wB0 = my.wc0 - wB1, wA1 = my.wr1 - wB1, wA0 = 1.f - my.wc0 - wA1;
      m2 = pack2(wA0 * wt_my, wB0 * wt_my); m3 = pack2(wA1 * wt_my, wB1 * wt_my); }  // XY
    { float wB1 = my.wc1 * my.wr2, wB0 = my.wc1 - wB1, wA1 = my.wr2 - wB1, wA0 = 1.f - my.wc1 - wA1;
      m4 = pack2(wA0 * wt_my, wB0 * wt_my); m5 = pack2(wA1 * wt_my, wB1 * wt_my); }  // YZ

    // wsum = sum of group's 8 sample weights (butterfly within 8-lane group)
    float wsum = wt_my;
    wsum += __shfl_xor(wsum, 1, 64);
    wsum += __shfl_xor(wsum, 2, 64);
    wsum += __shfl_xor(wsum, 4, 64);

    // ---- s-loop, depth-1 prefetch; fdot2 accumulates straight into wa ----
    f4 wa; wa.lo = (v2f){0.f, 0.f}; wa.hi = (v2f){0.f, 0.f};
    SampB cur, nxt;
    {
        int src = base;        // s = 0
        cur.u[0] = ldtap(tpb, __shfl(my.o0, src, 64) + lane16);
        cur.u[1] = ldtap(tpb, __shfl(my.o1, src, 64) + lane16);
        cur.u[2] = ldtap(tpb, __shfl(my.o2, src, 64) + lane16);
        cur.u[3] = ldtap(tpb, __shfl(my.o3, src, 64) + lane16);
        cur.u[4] = ldtap(tpb, __shfl(my.o4, src, 64) + lane16);
        cur.u[5] = ldtap(tpb, __shfl(my.o5, src, 64) + lane16);
    }
#pragma unroll
    for (int s = 0; s < SS; ++s) {
        if (s < SS - 1) {
            int src = base | (s + 1);
            nxt.u[0] = ldtap(tpb, __shfl(my.o0, src, 64) + lane16);
            nxt.u[1] = ldtap(tpb, __shfl(my.o1, src, 64) + lane16);
            nxt.u[2] = ldtap(tpb, __shfl(my.o2, src, 64) + lane16);
            nxt.u[3] = ldtap(tpb, __shfl(my.o3, src, 64) + lane16);
            nxt.u[4] = ldtap(tpb, __shfl(my.o4, src, 64) + lane16);
            nxt.u[5] = ldtap(tpb, __shfl(my.o5, src, 64) + lane16);
        }
        int src = base | s;
        eval_rowp(wa, cur.u[0], (unsigned)__shfl((int)m0, src, 64));
        eval_rowp(wa, cur.u[1], (unsigned)__shfl((int)m1, src, 64));
        eval_rowp(wa, cur.u[2], (unsigned)__shfl((int)m2, src, 64));
        eval_rowp(wa, cur.u[3], (unsigned)__shfl((int)m3, src, 64));
        eval_rowp(wa, cur.u[4], (unsigned)__shfl((int)m4, src, 64));
        eval_rowp(wa, cur.u[5], (unsigned)__shfl((int)m5, src, 64));
        if (s < SS - 1) cur = nxt;
    }

    // ---- out = wa @ (W_v@W_out) + wsum*(b_v@W_out) + b_out + feature ----
    f4 o;
    v2f ws2 = {wsum, wsum};
    {
        v2f bo  = {sbout[(lane << 2) + 0], sbout[(lane << 2) + 1]};
        v2f bv2 = {sbvw[(lane << 2) + 0], sbvw[(lane << 2) + 1]};
        o.lo = __builtin_elementwise_fma(ws2, bv2, bo) + feat.lo;
        v2f bo2 = {sbout[(lane << 2) + 2], sbout[(lane << 2) + 3]};
        v2f bv3 = {sbvw[(lane << 2) + 2], sbvw[(lane << 2) + 3]};
        o.hi = __builtin_elementwise_fma(ws2, bv3, bo2) + feat.hi;
    }
    // wa packed as f16 pairs: safe (final non-amplified linear, err ~0.005)
    unsigned pkLo = pack2(wa.lo.x, wa.lo.y);   // channels 4l, 4l+1
    unsigned pkHi = pack2(wa.hi.x, wa.hi.y);   // channels 4l+2, 4l+3
#pragma unroll
    for (int k2 = 0; k2 < 16; ++k2) {
        unsigned wb = (unsigned)__shfl((int)((k2 & 1) ? pkHi : pkLo), base | (k2 >> 1), 64);
        const uint4 wv = *(const uint4*)&sWc2h[k2][lane << 2];
        dot2_4(o, wv, wb);
    }

    if (qi < NS) {
        float* dst = out + ((size_t)b * NS + qi) * 32 + (lane << 2);
        *(float4*)dst = make_float4(o.lo.x, o.lo.y, o.hi.x, o.hi.y);
    }
}

extern "C" void kernel_launch(void* const* d_in, const int* in_sizes, int n_in,
                              void* d_out, int out_size, void* d_ws, size_t ws_size,
                              hipStream_t stream) {
    const float* qp   = (const float*)d_in[0];
    const float* cxz  = (const float*)d_in[1];
    const float* cxy  = (const float*)d_in[2];
    const float* cyz  = (const float*)d_in[3];
    const float* Woff = (const float*)d_in[4];
    const float* boff = (const float*)d_in[5];
    const float* Ww   = (const float*)d_in[6];
    const float* bw   = (const float*)d_in[7];
    const float* Wv   = (const float*)d_in[8];
    const float* bv   = (const float*)d_in[9];
    const float* Wout = (const float*)d_in[10];
    const float* bout = (const float*)d_in[11];
    float* out = (float*)d_out;

    unsigned* tp = (unsigned*)d_ws;
    float* Wc  = (float*)((char*)d_ws + (size_t)BS * 3 * RR * RR * CCH * 4);
    float* bvw = Wc + 1024;

    prep<<<BS * 3 * RR + 4, 256, 0, stream>>>(cxz, cxy, cyz, Wv, bv, Wout, tp, Wc, bvw);
    // even blockIdx -> batch 0, odd -> batch 1 (round-robin block->XCD dispatch
    // biases each XCD toward one batch's planes).
    int blocks_per_batch = (NS + 31) / 32;   // 32 queries per 256-thread block
    eda_main<<<2 * blocks_per_batch, 256, 0, stream>>>(qp, tp, Woff, boff, Ww, bw,
                                                       Wc, bvw, bout, out);
}